// Round 1
// baseline (426.711 us; speedup 1.0000x reference)
//
#include <hip/hip_runtime.h>

typedef __attribute__((ext_vector_type(8))) short short8v;
typedef __attribute__((ext_vector_type(4))) short short4v;
typedef __attribute__((ext_vector_type(4))) float floatx4;

#define S_    2048
#define DIM_  2048
#define NW_   6400   // wq 0..2047 | waq 2048..2079 | wak 2080..2111 | wk 2112..4159 | pad 4160..4351 | wv 4352..6399
#define VOFF_ 4352   // V region start (256-aligned so 256-wide tiles don't straddle)

#define ASG(p) ((__attribute__((address_space(1))) void*)(p))
#define ASL(p) ((__attribute__((address_space(3))) void*)(p))

__device__ __forceinline__ short f2bf(float f){
  union { float f; unsigned u; } c; c.f = f;
  unsigned u = c.u;
  unsigned r = (u + 0x7fffu + ((u >> 16) & 1u)) >> 16;
  return (short)r;
}
__device__ __forceinline__ float bf2f(short s){
  union { unsigned u; float f; } c; c.u = ((unsigned)(unsigned short)s) << 16;
  return c.f;
}

// ---------------- f32 -> bf16 convert (x) ----------------
__global__ __launch_bounds__(256) void cvt_k(const float* __restrict__ in,
                                             short* __restrict__ out, int n){
  int i = blockIdx.x*256 + threadIdx.x;
  int idx = i*4;
  if (idx >= n) return;
  floatx4 v = *(const floatx4*)(in + idx);
  short4v o;
  o[0]=f2bf(v[0]); o[1]=f2bf(v[1]); o[2]=f2bf(v[2]); o[3]=f2bf(v[3]);
  *(short4v*)(out + idx) = o;
}

// ---------------- all weights -> bf16, one launch ----------------
__global__ __launch_bounds__(256)
void cvt_w(const float* wq, const float* waq, const float* wak,
           const float* wk, const float* wv, const float* wo,
           short* Wcat, short* wob){
  const float* src; short* dst; int n;
  switch (blockIdx.y){
    case 0: src=wq;  dst=Wcat;                 n=4194304; break;
    case 1: src=waq; dst=Wcat+(size_t)2048*2048; n=65536; break;
    case 2: src=wak; dst=Wcat+(size_t)2080*2048; n=65536; break;
    case 3: src=wk;  dst=Wcat+(size_t)2112*2048; n=4194304; break;
    case 4: src=wv;  dst=Wcat+(size_t)4352*2048; n=4194304; break;
    case 5: src=wo;  dst=wob;                  n=4194304; break;
    default: { // zero pad rows 4160..4351 (192 rows)
      int idx = (blockIdx.x*256 + threadIdx.x)*4;
      if (idx < 393216){
        short4v z = {0,0,0,0};
        *(short4v*)(Wcat + (size_t)4160*2048 + idx) = z;
      }
      return;
    }
  }
  int idx = (blockIdx.x*256 + threadIdx.x)*4;
  if (idx >= n) return;
  floatx4 v = *(const floatx4*)(src + idx);
  short4v o;
  o[0]=f2bf(v[0]); o[1]=f2bf(v[1]); o[2]=f2bf(v[2]); o[3]=f2bf(v[3]);
  *(short4v*)(dst + idx) = o;
}

// ------------- fused QKV GEMM: C = X @ Wcat^T, 256x256 tile, 8-phase -------------
// T2 conflict-free 4-slot XOR swizzle (both-sides), T3/T4 counted vmcnt(4) (never 0
// in the main loop: 2 half-tiles = 4 loads stay in flight across every barrier),
// T5 setprio around MFMA clusters, T1 bijective XCD swizzle (400 blocks, 400%8==0).
// LDS: A[2buf][2kh][256][32]s + B same = 128 KiB. 512 thr = 8 waves (2M x 4N).
// Stage order per tile t (for t+1): p0:Ak0 p1:Bk0 p2:Ak1 p3:Bk1; waits at end of
// p1 (covers next p2/p3 reads) and p3 (covers next tile's p0/p1 reads).
__global__ __launch_bounds__(512,2)
void gemm_qkv(const short* __restrict__ A, const short* __restrict__ B,
              short* __restrict__ Cout, short* __restrict__ Vt){
  __shared__ short SH[65536];   // 128 KiB
  const int K = 2048;
  int tid = threadIdx.x;
  int wave = tid>>6, lane = tid&63, quad = lane>>4, l16 = lane&15;
  int wm_i = wave>>2, wn_i = wave&3;

  int bid = blockIdx.x;
  int swz = (bid&7)*50 + (bid>>3);      // 8 XCDs x 50 blocks, bijective
  int m0 = (swz & 15)*256;
  int n0 = (swz >> 4)*256;

  // staging: thread -> (row = tid>>2 [+128 for round 1], slot = tid&3)
  // LDS[row][slot] holds global k-group slot ^ sxr(row); source pre-swizzled.
  int srow = tid>>2;
  int sseg = (tid&3) ^ ((srow ^ (srow>>2)) & 3);
  const short* aS = A + (size_t)(m0 + srow)*K + sseg*8;
  const short* bS = B + (size_t)(n0 + srow)*K + sseg*8;
  int sdst = wave*512;                  // wave-uniform LDS base (shorts), lane*16B implicit

  // frag reads: row = (warp row base)+l16 -> sxr reduces to per-lane const
  int sx   = (l16 ^ (l16>>2)) & 3;
  int aoff = (wm_i*128 + l16)*32 + (quad^sx)*8;
  int boff = (wn_i*64  + l16)*32 + (quad^sx)*8;

  floatx4 acc[8][4] = {};

#define QSTAGE(src, chunk) do{ \
    __builtin_amdgcn_global_load_lds(ASG(src), ASL(&SH[(chunk)+sdst]), 16, 0, 0); \
    __builtin_amdgcn_global_load_lds(ASG((src) + (size_t)128*2048), ASL(&SH[(chunk)+sdst+4096]), 16, 0, 0); \
  }while(0)
#define QBAR  asm volatile("s_barrier" ::: "memory")
#define QW4   asm volatile("s_waitcnt vmcnt(4)" ::: "memory")

  // prologue: tile 0 fully staged; wait so Ak0+Bk0 (first 4 loads) have landed
  QSTAGE(aS,            0);
  QSTAGE(bS,        32768);
  QSTAGE(aS+32,      8192);
  QSTAGE(bS+32, 32768+8192);
  QW4; QBAR;

  for (int t=0; t<32; ++t){
    int buf = t&1, nb = buf^1;
    int k0n = ((t+1)&31)*64;            // wrapped for t=31: harmless re-stage, drained below
    int A0 = buf*16384,        A1 = A0+8192;
    int B0 = 32768+buf*16384,  B1 = B0+8192;
    int nA0 = nb*16384,        nA1 = nA0+8192;
    int nB0 = 32768+nb*16384,  nB1 = nB0+8192;
    short8v af[8], bf[2];

    // ---- p0: ks=0, nh=0 (10 ds_read) ----
    #pragma unroll
    for (int mf=0; mf<8; ++mf) af[mf] = *(short8v*)&SH[A0 + mf*512 + aoff];
    bf[0] = *(short8v*)&SH[B0 +   0 + boff];
    bf[1] = *(short8v*)&SH[B0 + 512 + boff];
    QSTAGE(aS + k0n, nA0);
    QBAR;
    __builtin_amdgcn_s_setprio(1);
    #pragma unroll
    for (int mf=0; mf<8; ++mf){
      acc[mf][0] = __builtin_amdgcn_mfma_f32_16x16x32_bf16(af[mf], bf[0], acc[mf][0], 0,0,0);
      acc[mf][1] = __builtin_amdgcn_mfma_f32_16x16x32_bf16(af[mf], bf[1], acc[mf][1], 0,0,0);
    }
    __builtin_amdgcn_s_setprio(0);
    QBAR;

    // ---- p1: ks=0, nh=1 (2 ds_read, af reused) ----
    bf[0] = *(short8v*)&SH[B0 + 1024 + boff];
    bf[1] = *(short8v*)&SH[B0 + 1536 + boff];
    QSTAGE(bS + k0n, nB0);
    QBAR;
    __builtin_amdgcn_s_setprio(1);
    #pragma unroll
    for (int mf=0; mf<8; ++mf){
      acc[mf][2] = __builtin_amdgcn_mfma_f32_16x16x32_bf16(af[mf], bf[0], acc[mf][2], 0,0,0);
      acc[mf][3] = __builtin_amdgcn_mfma_f32_16x16x32_bf16(af[mf], bf[1], acc[mf][3], 0,0,0);
    }
    __builtin_amdgcn_s_setprio(0);
    QW4;        // Ak1,Bk1 of this tile landed (allow 2 newest half-tiles in flight)
    QBAR;

    // ---- p2: ks=1, nh=0 (10 ds_read) ----
    #pragma unroll
    for (int mf=0; mf<8; ++mf) af[mf] = *(short8v*)&SH[A1 + mf*512 + aoff];
    bf[0] = *(short8v*)&SH[B1 +   0 + boff];
    bf[1] = *(short8v*)&SH[B1 + 512 + boff];
    QSTAGE(aS + k0n + 32, nA1);
    QBAR;
    __builtin_amdgcn_s_setprio(1);
    #pragma unroll
    for (int mf=0; mf<8; ++mf){
      acc[mf][0] = __builtin_amdgcn_mfma_f32_16x16x32_bf16(af[mf], bf[0], acc[mf][0], 0,0,0);
      acc[mf][1] = __builtin_amdgcn_mfma_f32_16x16x32_bf16(af[mf], bf[1], acc[mf][1], 0,0,0);
    }
    __builtin_amdgcn_s_setprio(0);
    QBAR;

    // ---- p3: ks=1, nh=1 (2 ds_read) ----
    bf[0] = *(short8v*)&SH[B1 + 1024 + boff];
    bf[1] = *(short8v*)&SH[B1 + 1536 + boff];
    QSTAGE(bS + k0n + 32, nB1);
    QBAR;
    __builtin_amdgcn_s_setprio(1);
    #pragma unroll
    for (int mf=0; mf<8; ++mf){
      acc[mf][2] = __builtin_amdgcn_mfma_f32_16x16x32_bf16(af[mf], bf[0], acc[mf][2], 0,0,0);
      acc[mf][3] = __builtin_amdgcn_mfma_f32_16x16x32_bf16(af[mf], bf[1], acc[mf][3], 0,0,0);
    }
    __builtin_amdgcn_s_setprio(0);
    QW4;        // next tile's Ak0,Bk0 landed
    QBAR;
  }

  __syncthreads();   // full drain (vmcnt 0): wrapped t=31 stages land before LDS reuse

  if (n0 < VOFF_){
    // Q | qh | kh | K | pad tiles: plain bf16 C-write
    #pragma unroll
    for (int mf=0; mf<8; ++mf)
      #pragma unroll
      for (int r=0; r<4; ++r){
        size_t gm = (size_t)(m0 + wm_i*128 + mf*16 + quad*4 + r);
        #pragma unroll
        for (int nf=0; nf<4; ++nf)
          Cout[gm*NW_ + n0 + wn_i*64 + nf*16 + l16] = f2bf(acc[mf][nf][r]);
      }
  } else {
    // V tiles: 256x256 transpose through LDS (reuses all 128 KiB), Vt[feat][token]
    short* T = SH;
    #pragma unroll
    for (int mf=0; mf<8; ++mf){
      int mb = wm_i*128 + mf*16 + quad*4;
      int mc = mb>>3, mi = mb&7;
      #pragma unroll
      for (int nf=0; nf<4; ++nf){
        int n = wn_i*64 + nf*16 + l16;
        short4v p;
        p[0]=f2bf(acc[mf][nf][0]); p[1]=f2bf(acc[mf][nf][1]);
        p[2]=f2bf(acc[mf][nf][2]); p[3]=f2bf(acc[mf][nf][3]);
        *(short4v*)&T[n*256 + ((mc ^ (n&31))*8) + mi] = p;
      }
    }
    __syncthreads();
    int f = tid>>1, half = tid&1;
    size_t vbase = (size_t)(n0 - VOFF_ + f)*4096 + m0;
    #pragma unroll
    for (int c=0; c<16; ++c){
      int cc = half*16 + c;
      short8v v = *(short8v*)&T[f*256 + ((cc ^ (f&31))*8)];
      *(short8v*)&Vt[vbase + cc*8] = v;
    }
  }
#undef QSTAGE
#undef QBAR
#undef QW4
}

// ------------- O GEMM (m97-style, 128x128) -------------
__global__ __launch_bounds__(256,4)
void gemm_nt_f32(const short* __restrict__ A, const short* __restrict__ B,
                 float* __restrict__ Cout, int M, int N, int K){
  __shared__ short As[128][64];
  __shared__ short Bs[128][64];
  int tid = threadIdx.x;
  int wave = tid>>6, lane = tid&63, quad = lane>>4, l16 = lane&15;
  int l7 = l16&7;
  int m0 = blockIdx.x*128, n0 = blockIdx.y*128;
  int wm = (wave>>1)*64, wn = (wave&1)*64;
  floatx4 acc[4][4] = {};

  int lr = lane>>3;
  int sw = (lane&7) ^ lr;
  const short* Abase = A + (size_t)(m0 + wave*32 + lr)*K + sw*8;
  const short* Bbase = B + (size_t)(n0 + wave*32 + lr)*K + sw*8;

  for (int k0 = 0; k0 < K; k0 += 64){
    __syncthreads();
    #pragma unroll
    for (int i=0;i<4;i++){
      __builtin_amdgcn_global_load_lds(ASG(Abase + (size_t)(i*8)*K + k0),
                                       ASL(&As[wave*32 + i*8][0]), 16, 0, 0);
      __builtin_amdgcn_global_load_lds(ASG(Bbase + (size_t)(i*8)*K + k0),
                                       ASL(&Bs[wave*32 + i*8][0]), 16, 0, 0);
    }
    __syncthreads();
    #pragma unroll
    for (int ks=0; ks<2; ks++){
      short8v af[4], bf[4];
      #pragma unroll
      for (int i=0;i<4;i++) af[i] = *(short8v*)&As[wm + i*16 + l16][((ks*4+quad)^l7)*8];
      #pragma unroll
      for (int j=0;j<4;j++) bf[j] = *(short8v*)&Bs[wn + j*16 + l16][((ks*4+quad)^l7)*8];
      #pragma unroll
      for (int i=0;i<4;i++)
        #pragma unroll
        for (int j=0;j<4;j++)
          acc[i][j] = __builtin_amdgcn_mfma_f32_16x16x32_bf16(af[i], bf[j], acc[i][j], 0,0,0);
    }
  }
  #pragma unroll
  for (int i=0;i<4;i++)
    #pragma unroll
    for (int r=0;r<4;r++){
      int gm = m0 + wm + i*16 + quad*4 + r;
      #pragma unroll
      for (int j=0;j<4;j++){
        int gn = n0 + wn + j*16 + l16;
        Cout[(size_t)gm*N + gn] = acc[i][j][r];
      }
    }
}

// ---------------- RoPE on K only (in XQKV, stride NW_, offset 2112) --------
__global__ __launch_bounds__(256) void rope_k(short* __restrict__ X,
                                              const float* __restrict__ fcos,
                                              const float* __restrict__ fsin){
  int i = blockIdx.x*256 + threadIdx.x;
  int row = i >> 10;
  int p = i & 1023;
  int s = row & (S_-1);
  int pp = p & 63;
  float c = fcos[s*64+pp], sn = fsin[s*64+pp];
  size_t a = (size_t)row*NW_ + 2112 + p*2;
  int v = *(int*)(X + a);
  float re = bf2f((short)(v & 0xffff)), im = bf2f((short)(v >> 16));
  float orr = re*c - im*sn, oi = re*sn + im*c;
  *(int*)(X + a) = ((int)(unsigned short)f2bf(oi) << 16) | (unsigned short)f2bf(orr);
}

// ---------------- gate precompute: G[b][kt][q][l16*4+j] = sigmoid(qh.kh) ----
__global__ __launch_bounds__(256)
void gate_k(const short* __restrict__ X, short* __restrict__ G){
  int kt = blockIdx.x, qt = blockIdx.y, b = blockIdx.z;
  if (kt > qt) return;
  int tid = threadIdx.x, wave = tid>>6, lane = tid&63, quad = lane>>4, l16 = lane&15;
  const float NL2E = -1.44269504f;

  short8v qh = *(const short8v*)&X[(size_t)(b*2048 + qt*64 + wave*16 + l16)*NW_ + 2048 + quad*8];
  floatx4 am[4];
  #pragma unroll
  for (int j=0;j<4;j++){
    short8v kh = *(const short8v*)&X[(size_t)(b*2048 + kt*64 + j*16 + l16)*NW_ + 2080 + quad*8];
    floatx4 z = {0.f,0.f,0.f,0.f};
    am[j] = __builtin_amdgcn_mfma_f32_16x16x32_bf16(qh, kh, z, 0,0,0);
  }
  short* Gd = G + (((size_t)(b*32 + kt)*2048) + qt*64 + wave*16 + quad*4)*64 + l16*4;
  #pragma unroll
  for (int r=0;r<4;r++){
    short4v sv;
    #pragma unroll
    for (int j=0;j<4;j++){
      float g = __builtin_amdgcn_rcpf(1.f + __builtin_amdgcn_exp2f(am[j][r]*NL2E));
      sv[j] = f2bf(g);
    }
    *(short4v*)(Gd + (size_t)r*64) = sv;
  }
}

// ---------------- Flash attention v4: BQ=64, XCD-local heads, 2 blocks/CU ---
// grid = (16 h, 16 pi, 2 b): linear id = h + 16*pi + 256*b -> XCD = h%8, so
// all blocks of head h share one XCD's L2 (K+V per XCD = 4 MB = L2 size).
// Paired q-tiles (31-pi, pi): every block runs exactly 33 strips. Single-buffer
// m97-style staging (dbuf measured neutral; keeps LDS at 41 KB -> 2 blocks/CU).
__global__ __launch_bounds__(256,2)
void flash_k(const short* __restrict__ Qc, const short* __restrict__ Vt,
             const short* __restrict__ G, const float* __restrict__ fcos,
             const float* __restrict__ fsin, short* __restrict__ O){
  int h = blockIdx.x, pi = blockIdx.y, b = blockIdx.z;
  int tid = threadIdx.x, wave = tid>>6, lane = tid&63, quad = lane>>4, l16 = lane&15;
  int l7 = l16&7;

  __shared__ short Ks [64][128];     // 16 KB
  __shared__ short Vts[128][64];     // 16 KB
  __shared__ short Ps [4][16][72];   // 9 KB

  const float CS = 1.44269504f * 0.08838834764831845f;  // log2(e)/sqrt(128)

  for (int ph = 0; ph < 2; ph++){
    int qt = ph ? pi : 31 - pi;
    int srow = qt*64 + wave*16 + l16;
    size_t qrow = (size_t)(b*2048 + srow);
    short8v qf[4];
    #pragma unroll
    for (int ks=0;ks<4;ks++)
      qf[ks] = *(const short8v*)&Qc[qrow*NW_ + h*128 + ks*32 + quad*8];
    // fused RoPE on Q fragments (pairs are lane-local)
    #pragma unroll
    for (int ks=0;ks<4;ks++)
      #pragma unroll
      for (int jj=0;jj<4;jj++){
        float re = bf2f(qf[ks][2*jj]), im = bf2f(qf[ks][2*jj+1]);
        int p = ks*16 + quad*4 + jj;
        float c = fcos[srow*64 + p], sn = fsin[srow*64 + p];
        qf[ks][2*jj]   = f2bf(re*c - im*sn);
        qf[ks][2*jj+1] = f2bf(re*sn + im*c);
      }

    floatx4 oacc[8] = {};
    float lp[4] = {0.f,0.f,0.f,0.f};

    for (int kt=0; kt<=qt; kt++){
      int k0 = kt*64;
      __syncthreads();   // previous strip's LDS readers done
      {
        const short* Ksrc = Qc + ((size_t)(b*2048 + k0 + wave*16))*NW_ + 2112 + h*128;
        int r4 = lane>>4, c16 = lane&15;
        #pragma unroll
        for (int j=0;j<4;j++)
          __builtin_amdgcn_global_load_lds(
            ASG(Ksrc + (size_t)(j*4 + r4)*NW_ + ((c16 ^ r4 ^ ((j&1)*4))*8)),
            ASL(&Ks[wave*16 + j*4][0]), 16, 0, 0);
        const short* Vsrc = Vt + ((size_t)(h*128 + wave*32 + (lane>>3)))*4096 + b*2048 + k0
                            + (((lane&7) ^ (lane>>3))*8);
        #pragma unroll
        for (int j=0;j<4;j++)
          __builtin_amdgcn_global_load_lds(
            ASG(Vsrc + (size_t)(j*8)*4096),
            ASL(&Vts[wave*32 + j*8][0]), 16, 0, 0);
      }
      __syncthreads();   // staging complete (implicit vmcnt(0) drain)

      // gate loads (coalesced 8B per lane-row, L2-hot)
      const short* gb = G + (((size_t)(b*32 + kt)*2048) + qt*64 + wave*16 + quad*4)*64 + l16*4;
      short4v g4[4];
      #pragma unroll
      for (int r=0;r<4;r++) g4[r] = *(const short4v*)(gb + (size_t)r*64);

      // ---- QK^T ----
      floatx4 sacc[4] = {};
      #pragma unroll
      for (int j=0;j<4;j++)
        #pragma unroll
        for (int ks2=0;ks2<4;ks2++){
          short8v kf = *(short8v*)&Ks[j*16+l16][((ks2*4+quad)^l7)*8];
          sacc[j] = __builtin_amdgcn_mfma_f32_16x16x32_bf16(qf[ks2], kf, sacc[j], 0,0,0);
        }

      // ---- mask + exp + gate -> Ps ----
      bool diag = (kt == qt);
      int qbase = wave*16 + quad*4;
      #pragma unroll
      for (int j=0;j<4;j++){
        int kin = j*16 + l16;
        #pragma unroll
        for (int r=0;r<4;r++){
          bool keep = !diag || (kin <= qbase + r);
          float p = keep ? __builtin_amdgcn_exp2f(sacc[j][r]*CS) : 0.f;
          lp[r] += p;
          Ps[wave][quad*4+r][j*16+l16] = f2bf(p * bf2f(g4[r][j]));
        }
      }

      // ---- P·V ----
      #pragma unroll
      for (int ks2=0; ks2<2; ks2++){
        short8v pf = *(short8v*)&Ps[wave][l16][ks2*32 + quad*8];
        #pragma unroll
        for (int dt=0; dt<8; dt++){
          short8v vf = *(short8v*)&Vts[dt*16 + l16][((ks2*4+quad)^l7)*8];
          oacc[dt] = __builtin_amdgcn_mfma_f32_16x16x32_bf16(pf, vf, oacc[dt], 0,0,0);
        }
      }
    }

    #pragma unroll
    for (int r=0;r<4;r++)
      #pragma unroll
      for (int off=1; off<16; off<<=1)
        lp[r] += __shfl_xor(lp[r], off, 64);
    #pragma unroll
    for (int r=0;r<4;r++){
      float inv = __builtin_amdgcn_rcpf(lp[r]);
      size_t orow = (size_t)(b*2048 + qt*64 + wave*16 + quad*4 + r);
      #pragma unroll
      for (int dt=0;dt<8;dt++)
        O[orow*2048 + h*128 + dt*16 + l16] = f2bf(oacc[dt][r]*inv);
    }
  }
}

// ---------------- launch ----------------
extern "C" void kernel_launch(void* const* d_in, const int* in_sizes, int n_in,
                              void* d_out, int out_size, void* d_ws, size_t ws_size,
                              hipStream_t stream){
  const float* x    = (const float*)d_in[0];
  const float* fcos = (const float*)d_in[2];
  const float* fsin = (const float*)d_in[3];
  const float* wq   = (const float*)d_in[4];
  const float* wk   = (const float*)d_in[5];
  const float* wv   = (const float*)d_in[6];
  const float* wo   = (const float*)d_in[7];
  const float* waq  = (const float*)d_in[8];
  const float* wak  = (const float*)d_in[9];
  float* out = (float*)d_out;

  char* ws = (char*)d_ws;
  size_t off = 0;
  short* xb   = (short*)(ws + off); off += (size_t)4096*2048*2;   // x bf16; later G (gate)
  short* Wcat = (short*)(ws + off); off += (size_t)NW_*2048*2;    // fused weights; later O
  short* wob  = (short*)(ws + off); off += (size_t)2048*2048*2;
  short* XQKV = (short*)(ws + off); off += (size_t)4096*NW_*2;    // [Q|qh|kh|K|pad|(V unused)]
  short* Vtb  = (short*)(ws + off); off += (size_t)2048*4096*2;   // V transposed
  short* G    = xb;    // gate overlays xb (x dead after gemm_qkv)
  short* Ob   = Wcat;  // flash output overlays Wcat (dead after gemm_qkv)

  cvt_k<<<8192,256,0,stream>>>(x, xb, 8388608);
  cvt_w<<<dim3(4096,7),256,0,stream>>>(wq, waq, wak, wk, wv, wo, Wcat, wob);

  gemm_qkv<<<dim3(400),512,0,stream>>>(xb, Wcat, XQKV, Vtb);

  rope_k<<<16384,256,0,stream>>>(XQKV, fcos, fsin);
  gate_k<<<dim3(32,32,2),256,0,stream>>>(XQKV, G);

  flash_k<<<dim3(16,16,2),256,0,stream>>>(XQKV, Vtb, G, fcos, fsin, Ob);

  gemm_nt_f32<<<dim3(32,16),256,0,stream>>>(Ob, wob, out, 4096, 2048, 2048);
}

// Round 3
// 399.802 us; speedup vs baseline: 1.0673x; 1.0673x over previous
//
#include <hip/hip_runtime.h>

typedef __attribute__((ext_vector_type(8))) short short8v;
typedef __attribute__((ext_vector_type(4))) short short4v;
typedef __attribute__((ext_vector_type(4))) float floatx4;

#define S_    2048
#define DIM_  2048
#define NW_   6400   // wq 0..2047 | waq 2048..2079 | wak 2080..2111 | wk 2112..4159 | pad 4160..4351 | wv 4352..6399
#define VOFF_ 4352   // V region start (256-aligned so 256-wide tiles don't straddle)

#define ASG(p) ((__attribute__((address_space(1))) void*)(p))
#define ASL(p) ((__attribute__((address_space(3))) void*)(p))

__device__ __forceinline__ short f2bf(float f){
  union { float f; unsigned u; } c; c.f = f;
  unsigned u = c.u;
  unsigned r = (u + 0x7fffu + ((u >> 16) & 1u)) >> 16;
  return (short)r;
}
__device__ __forceinline__ float bf2f(short s){
  union { unsigned u; float f; } c; c.u = ((unsigned)(unsigned short)s) << 16;
  return c.f;
}

// ---------------- f32 -> bf16 convert (x) ----------------
__global__ __launch_bounds__(256) void cvt_k(const float* __restrict__ in,
                                             short* __restrict__ out, int n){
  int i = blockIdx.x*256 + threadIdx.x;
  int idx = i*4;
  if (idx >= n) return;
  floatx4 v = *(const floatx4*)(in + idx);
  short4v o;
  o[0]=f2bf(v[0]); o[1]=f2bf(v[1]); o[2]=f2bf(v[2]); o[3]=f2bf(v[3]);
  *(short4v*)(out + idx) = o;
}

// ---------------- all weights -> bf16, one launch ----------------
__global__ __launch_bounds__(256)
void cvt_w(const float* wq, const float* waq, const float* wak,
           const float* wk, const float* wv, const float* wo,
           short* Wcat, short* wob){
  const float* src; short* dst; int n;
  switch (blockIdx.y){
    case 0: src=wq;  dst=Wcat;                 n=4194304; break;
    case 1: src=waq; dst=Wcat+(size_t)2048*2048; n=65536; break;
    case 2: src=wak; dst=Wcat+(size_t)2080*2048; n=65536; break;
    case 3: src=wk;  dst=Wcat+(size_t)2112*2048; n=4194304; break;
    case 4: src=wv;  dst=Wcat+(size_t)4352*2048; n=4194304; break;
    case 5: src=wo;  dst=wob;                  n=4194304; break;
    default: { // zero pad rows 4160..4351 (192 rows)
      int idx = (blockIdx.x*256 + threadIdx.x)*4;
      if (idx < 393216){
        short4v z = {0,0,0,0};
        *(short4v*)(Wcat + (size_t)4160*2048 + idx) = z;
      }
      return;
    }
  }
  int idx = (blockIdx.x*256 + threadIdx.x)*4;
  if (idx >= n) return;
  floatx4 v = *(const floatx4*)(src + idx);
  short4v o;
  o[0]=f2bf(v[0]); o[1]=f2bf(v[1]); o[2]=f2bf(v[2]); o[3]=f2bf(v[3]);
  *(short4v*)(dst + idx) = o;
}

// ------------- fused QKV GEMM: C = X @ Wcat^T, 256x256 tile, pipelined 4-phase ----
// Frag ds_reads issued ONE PHASE AHEAD of their consuming MFMA (m201's actual
// schedule): the compiler then emits counted lgkmcnt (never 0) before each MFMA
// cluster and LDS latency hides under the previous phase's MFMA. Reads/phase are
// balanced 4/8/4/8; one barrier per phase; vmcnt(4) only where it validates the
// chunk the NEXT phase reads (chunk lifetimes have >=2 barriers of slack).
// Chunks (shorts): A0=buf*16384, A1=A0+8192, B0=32768+buf*16384, B1=B0+8192.
// Stage points: P1->B0(t+1), P2->A1(t+1), P3->B1(t+1), P0->A0(t+2, into cur buf).
__global__ __launch_bounds__(512,2)
void gemm_qkv(const short* __restrict__ A, const short* __restrict__ B,
              short* __restrict__ Cout, short* __restrict__ Vt){
  __shared__ short SH[65536];   // 128 KiB
  const int K = 2048;
  int tid = threadIdx.x;
  int wave = tid>>6, lane = tid&63, quad = lane>>4, l16 = lane&15;
  int wm_i = wave>>2, wn_i = wave&3;

  int bid = blockIdx.x;
  int swz = (bid&7)*50 + (bid>>3);      // 8 XCDs x 50 blocks, bijective
  int m0 = (swz & 15)*256;
  int n0 = (swz >> 4)*256;

  // staging: thread -> (row = tid>>2 [+128 for 2nd gload], slot = tid&3)
  int srow = tid>>2;
  int sseg = (tid&3) ^ ((srow ^ (srow>>2)) & 3);
  const short* aS = A + (size_t)(m0 + srow)*K + sseg*8;
  const short* bS = B + (size_t)(n0 + srow)*K + sseg*8;
  int sdst = wave*512;                  // wave-uniform LDS base (shorts)

  int sx   = (l16 ^ (l16>>2)) & 3;
  int aoff = (wm_i*128 + l16)*32 + (quad^sx)*8;
  int boff = (wn_i*64  + l16)*32 + (quad^sx)*8;

  floatx4 acc[8][4] = {};
  short8v afA[8], afB[8], bfA[4], bfB[4];

#define QSTAGE(src, chunk) do{ \
    __builtin_amdgcn_global_load_lds(ASG(src), ASL(&SH[(chunk)+sdst]), 16, 0, 0); \
    __builtin_amdgcn_global_load_lds(ASG((src) + (size_t)128*2048), ASL(&SH[(chunk)+sdst+4096]), 16, 0, 0); \
  }while(0)
#define QBAR  asm volatile("s_barrier" ::: "memory")
#define QW4   asm volatile("s_waitcnt vmcnt(4)" ::: "memory")
#define MFMA_ __builtin_amdgcn_mfma_f32_16x16x32_bf16

  // ---- prologue: stage tile0 (4 half-chunks); validate A0/B0; preload P1 ops;
  //      stage A0 of tile1 (mimics steady-state P0). queue on loop entry:
  //      {A1_0, B1_0, A0_1} = 6 loads outstanding.
  QSTAGE(aS,            0);
  QSTAGE(bS,        32768);
  QSTAGE(aS+32,      8192);
  QSTAGE(bS+32, 32768+8192);
  QW4;              // A0_0, B0_0 landed (A1_0, B1_0 still in flight)
  QBAR;
  #pragma unroll
  for (int mf=0; mf<4; ++mf) afA[mf] = *(short8v*)&SH[0     + mf*512 + aoff];
  #pragma unroll
  for (int nf=0; nf<4; ++nf) bfA[nf] = *(short8v*)&SH[32768 + nf*512 + boff];
  QSTAGE(aS + 64, 16384);   // A0 of tile 1 -> buf1

  for (int t=0; t<32; ++t){
    int buf = t&1, nb = buf^1;
    int A0c = buf*16384,        A1c = A0c+8192;
    int B0c = 32768+buf*16384,  B1c = B0c+8192;
    int A0n = nb*16384,         A1n = A0n+8192;
    int B0n = 32768+nb*16384,   B1n = B0n+8192;
    int kn  = ((t+1)&31)*64;    // stages for tile t+1 (t=31 wraps: garbage, drained)
    int kn2 = ((t+2)&31)*64;    // stage A0 for tile t+2 (into cur buf)

    // ---- P1: reads afA[4..7] (A0c, for P2); stage B0n; QW4 validates A1c,B1c;
    //          MFMA ks0 x m0-3 (ops read in prev P0/prologue)
    #pragma unroll
    for (int mf=4; mf<8; ++mf) afA[mf] = *(short8v*)&SH[A0c + mf*512 + aoff];
    QSTAGE(bS + kn, B0n);
    QW4;              // drains A1c,B1c (outstanding -> {A0n,B0n})
    QBAR;
    __builtin_amdgcn_s_setprio(1);
    #pragma unroll
    for (int mf=0; mf<4; ++mf)
      #pragma unroll
      for (int nf=0; nf<4; ++nf)
        acc[mf][nf] = MFMA_(afA[mf], bfA[nf], acc[mf][nf], 0,0,0);
    __builtin_amdgcn_s_setprio(0);

    // ---- P2: reads afB[0..3] (A1c) + bfB[0..3] (B1c) (for P3); stage A1n;
    //          MFMA ks0 x m4-7
    #pragma unroll
    for (int mf=0; mf<4; ++mf) afB[mf] = *(short8v*)&SH[A1c + mf*512 + aoff];
    #pragma unroll
    for (int nf=0; nf<4; ++nf) bfB[nf] = *(short8v*)&SH[B1c + nf*512 + boff];
    QSTAGE(aS + kn + 32, A1n);
    QBAR;
    __builtin_amdgcn_s_setprio(1);
    #pragma unroll
    for (int mf=4; mf<8; ++mf)
      #pragma unroll
      for (int nf=0; nf<4; ++nf)
        acc[mf][nf] = MFMA_(afA[mf], bfA[nf], acc[mf][nf], 0,0,0);
    __builtin_amdgcn_s_setprio(0);

    // ---- P3: reads afB[4..7] (A1c, for P0); stage B1n; QW4 validates A0n,B0n;
    //          MFMA ks1 x m0-3
    #pragma unroll
    for (int mf=4; mf<8; ++mf) afB[mf] = *(short8v*)&SH[A1c + mf*512 + aoff];
    QSTAGE(bS + kn + 32, B1n);
    QW4;              // drains A0n,B0n (outstanding -> {A1n,B1n})
    QBAR;
    __builtin_amdgcn_s_setprio(1);
    #pragma unroll
    for (int mf=0; mf<4; ++mf)
      #pragma unroll
      for (int nf=0; nf<4; ++nf)
        acc[mf][nf] = MFMA_(afB[mf], bfB[nf], acc[mf][nf], 0,0,0);
    __builtin_amdgcn_s_setprio(0);

    // ---- P0: reads afA[0..3] + bfA[0..3] from NEXT tile's A0/B0 (validated);
    //          stage A0 of t+2 over cur A0 (last read 3 barriers ago);
    //          MFMA ks1 x m4-7
    #pragma unroll
    for (int mf=0; mf<4; ++mf) afA[mf] = *(short8v*)&SH[A0n + mf*512 + aoff];
    #pragma unroll
    for (int nf=0; nf<4; ++nf) bfA[nf] = *(short8v*)&SH[B0n + nf*512 + boff];
    QSTAGE(aS + kn2, A0c);
    QBAR;
    __builtin_amdgcn_s_setprio(1);
    #pragma unroll
    for (int mf=4; mf<8; ++mf)
      #pragma unroll
      for (int nf=0; nf<4; ++nf)
        acc[mf][nf] = MFMA_(afB[mf], bfB[nf], acc[mf][nf], 0,0,0);
    __builtin_amdgcn_s_setprio(0);
  }

  __syncthreads();   // full drain (vmcnt0+lgkm0): wrapped stages land before LDS reuse

  if (n0 < VOFF_){
    // Q | qh | kh | K | pad tiles: plain bf16 C-write
    #pragma unroll
    for (int mf=0; mf<8; ++mf)
      #pragma unroll
      for (int r=0; r<4; ++r){
        size_t gm = (size_t)(m0 + wm_i*128 + mf*16 + quad*4 + r);
        #pragma unroll
        for (int nf=0; nf<4; ++nf)
          Cout[gm*NW_ + n0 + wn_i*64 + nf*16 + l16] = f2bf(acc[mf][nf][r]);
      }
  } else {
    // V tiles: 256x256 transpose through LDS (reuses all 128 KiB), Vt[feat][token]
    short* T = SH;
    #pragma unroll
    for (int mf=0; mf<8; ++mf){
      int mb = wm_i*128 + mf*16 + quad*4;
      int mc = mb>>3, mi = mb&7;
      #pragma unroll
      for (int nf=0; nf<4; ++nf){
        int n = wn_i*64 + nf*16 + l16;
        short4v p;
        p[0]=f2bf(acc[mf][nf][0]); p[1]=f2bf(acc[mf][nf][1]);
        p[2]=f2bf(acc[mf][nf][2]); p[3]=f2bf(acc[mf][nf][3]);
        *(short4v*)&T[n*256 + ((mc ^ (n&31))*8) + mi] = p;
      }
    }
    __syncthreads();
    int f = tid>>1, half = tid&1;
    size_t vbase = (size_t)(n0 - VOFF_ + f)*4096 + m0;
    #pragma unroll
    for (int c=0; c<16; ++c){
      int cc = half*16 + c;
      short8v v = *(short8v*)&T[f*256 + ((cc ^ (f&31))*8)];
      *(short8v*)&Vt[vbase + cc*8] = v;
    }
  }
#undef QSTAGE
#undef QBAR
#undef QW4
#undef MFMA_
}

// ------------- O GEMM (m97-style, 128x128) -------------
__global__ __launch_bounds__(256,4)
void gemm_nt_f32(const short* __restrict__ A, const short* __restrict__ B,
                 float* __restrict__ Cout, int M, int N, int K){
  __shared__ short As[128][64];
  __shared__ short Bs[128][64];
  int tid = threadIdx.x;
  int wave = tid>>6, lane = tid&63, quad = lane>>4, l16 = lane&15;
  int l7 = l16&7;
  int m0 = blockIdx.x*128, n0 = blockIdx.y*128;
  int wm = (wave>>1)*64, wn = (wave&1)*64;
  floatx4 acc[4][4] = {};

  int lr = lane>>3;
  int sw = (lane&7) ^ lr;
  const short* Abase = A + (size_t)(m0 + wave*32 + lr)*K + sw*8;
  const short* Bbase = B + (size_t)(n0 + wave*32 + lr)*K + sw*8;

  for (int k0 = 0; k0 < K; k0 += 64){
    __syncthreads();
    #pragma unroll
    for (int i=0;i<4;i++){
      __builtin_amdgcn_global_load_lds(ASG(Abase + (size_t)(i*8)*K + k0),
                                       ASL(&As[wave*32 + i*8][0]), 16, 0, 0);
      __builtin_amdgcn_global_load_lds(ASG(Bbase + (size_t)(i*8)*K + k0),
                                       ASL(&Bs[wave*32 + i*8][0]), 16, 0, 0);
    }
    __syncthreads();
    #pragma unroll
    for (int ks=0; ks<2; ks++){
      short8v af[4], bf[4];
      #pragma unroll
      for (int i=0;i<4;i++) af[i] = *(short8v*)&As[wm + i*16 + l16][((ks*4+quad)^l7)*8];
      #pragma unroll
      for (int j=0;j<4;j++) bf[j] = *(short8v*)&Bs[wn + j*16 + l16][((ks*4+quad)^l7)*8];
      #pragma unroll
      for (int i=0;i<4;i++)
        #pragma unroll
        for (int j=0;j<4;j++)
          acc[i][j] = __builtin_amdgcn_mfma_f32_16x16x32_bf16(af[i], bf[j], acc[i][j], 0,0,0);
    }
  }
  #pragma unroll
  for (int i=0;i<4;i++)
    #pragma unroll
    for (int r=0;r<4;r++){
      int gm = m0 + wm + i*16 + quad*4 + r;
      #pragma unroll
      for (int j=0;j<4;j++){
        int gn = n0 + wn + j*16 + l16;
        Cout[(size_t)gm*N + gn] = acc[i][j][r];
      }
    }
}

// ---------------- RoPE on K only (in XQKV, stride NW_, offset 2112) --------
__global__ __launch_bounds__(256) void rope_k(short* __restrict__ X,
                                              const float* __restrict__ fcos,
                                              const float* __restrict__ fsin){
  int i = blockIdx.x*256 + threadIdx.x;
  int row = i >> 10;
  int p = i & 1023;
  int s = row & (S_-1);
  int pp = p & 63;
  float c = fcos[s*64+pp], sn = fsin[s*64+pp];
  size_t a = (size_t)row*NW_ + 2112 + p*2;
  int v = *(int*)(X + a);
  float re = bf2f((short)(v & 0xffff)), im = bf2f((short)(v >> 16));
  float orr = re*c - im*sn, oi = re*sn + im*c;
  *(int*)(X + a) = ((int)(unsigned short)f2bf(oi) << 16) | (unsigned short)f2bf(orr);
}

// ---------------- gate precompute: G[b][kt][q][l16*4+j] = sigmoid(qh.kh) ----
__global__ __launch_bounds__(256)
void gate_k(const short* __restrict__ X, short* __restrict__ G){
  int kt = blockIdx.x, qt = blockIdx.y, b = blockIdx.z;
  if (kt > qt) return;
  int tid = threadIdx.x, wave = tid>>6, lane = tid&63, quad = lane>>4, l16 = lane&15;
  const float NL2E = -1.44269504f;

  short8v qh = *(const short8v*)&X[(size_t)(b*2048 + qt*64 + wave*16 + l16)*NW_ + 2048 + quad*8];
  floatx4 am[4];
  #pragma unroll
  for (int j=0;j<4;j++){
    short8v kh = *(const short8v*)&X[(size_t)(b*2048 + kt*64 + j*16 + l16)*NW_ + 2080 + quad*8];
    floatx4 z = {0.f,0.f,0.f,0.f};
    am[j] = __builtin_amdgcn_mfma_f32_16x16x32_bf16(qh, kh, z, 0,0,0);
  }
  short* Gd = G + (((size_t)(b*32 + kt)*2048) + qt*64 + wave*16 + quad*4)*64 + l16*4;
  #pragma unroll
  for (int r=0;r<4;r++){
    short4v sv;
    #pragma unroll
    for (int j=0;j<4;j++){
      float g = __builtin_amdgcn_rcpf(1.f + __builtin_amdgcn_exp2f(am[j][r]*NL2E));
      sv[j] = f2bf(g);
    }
    *(short4v*)(Gd + (size_t)r*64) = sv;
  }
}

// ---------------- Flash attention v4: BQ=64, XCD-local heads, 2 blocks/CU ---
__global__ __launch_bounds__(256,2)
void flash_k(const short* __restrict__ Qc, const short* __restrict__ Vt,
             const short* __restrict__ G, const float* __restrict__ fcos,
             const float* __restrict__ fsin, short* __restrict__ O){
  int h = blockIdx.x, pi = blockIdx.y, b = blockIdx.z;
  int tid = threadIdx.x, wave = tid>>6, lane = tid&63, quad = lane>>4, l16 = lane&15;
  int l7 = l16&7;

  __shared__ short Ks [64][128];     // 16 KB
  __shared__ short Vts[128][64];     // 16 KB
  __shared__ short Ps [4][16][72];   // 9 KB

  const float CS = 1.44269504f * 0.08838834764831845f;  // log2(e)/sqrt(128)

  for (int ph = 0; ph < 2; ph++){
    int qt = ph ? pi : 31 - pi;
    int srow = qt*64 + wave*16 + l16;
    size_t qrow = (size_t)(b*2048 + srow);
    short8v qf[4];
    #pragma unroll
    for (int ks=0;ks<4;ks++)
      qf[ks] = *(const short8v*)&Qc[qrow*NW_ + h*128 + ks*32 + quad*8];
    // fused RoPE on Q fragments (pairs are lane-local)
    #pragma unroll
    for (int ks=0;ks<4;ks++)
      #pragma unroll
      for (int jj=0;jj<4;jj++){
        float re = bf2f(qf[ks][2*jj]), im = bf2f(qf[ks][2*jj+1]);
        int p = ks*16 + quad*4 + jj;
        float c = fcos[srow*64 + p], sn = fsin[srow*64 + p];
        qf[ks][2*jj]   = f2bf(re*c - im*sn);
        qf[ks][2*jj+1] = f2bf(re*sn + im*c);
      }

    floatx4 oacc[8] = {};
    float lp[4] = {0.f,0.f,0.f,0.f};

    for (int kt=0; kt<=qt; kt++){
      int k0 = kt*64;
      __syncthreads();   // previous strip's LDS readers done
      {
        const short* Ksrc = Qc + ((size_t)(b*2048 + k0 + wave*16))*NW_ + 2112 + h*128;
        int r4 = lane>>4, c16 = lane&15;
        #pragma unroll
        for (int j=0;j<4;j++)
          __builtin_amdgcn_global_load_lds(
            ASG(Ksrc + (size_t)(j*4 + r4)*NW_ + ((c16 ^ r4 ^ ((j&1)*4))*8)),
            ASL(&Ks[wave*16 + j*4][0]), 16, 0, 0);
        const short* Vsrc = Vt + ((size_t)(h*128 + wave*32 + (lane>>3)))*4096 + b*2048 + k0
                            + (((lane&7) ^ (lane>>3))*8);
        #pragma unroll
        for (int j=0;j<4;j++)
          __builtin_amdgcn_global_load_lds(
            ASG(Vsrc + (size_t)(j*8)*4096),
            ASL(&Vts[wave*32 + j*8][0]), 16, 0, 0);
      }
      __syncthreads();   // staging complete (implicit vmcnt(0) drain)

      // gate loads (coalesced 8B per lane-row, L2-hot)
      const short* gb = G + (((size_t)(b*32 + kt)*2048) + qt*64 + wave*16 + quad*4)*64 + l16*4;
      short4v g4[4];
      #pragma unroll
      for (int r=0;r<4;r++) g4[r] = *(const short4v*)(gb + (size_t)r*64);

      // ---- QK^T ----
      floatx4 sacc[4] = {};
      #pragma unroll
      for (int j=0;j<4;j++)
        #pragma unroll
        for (int ks2=0;ks2<4;ks2++){
          short8v kf = *(short8v*)&Ks[j*16+l16][((ks2*4+quad)^l7)*8];
          sacc[j] = __builtin_amdgcn_mfma_f32_16x16x32_bf16(qf[ks2], kf, sacc[j], 0,0,0);
        }

      // ---- mask + exp + gate -> Ps ----
      bool diag = (kt == qt);
      int qbase = wave*16 + quad*4;
      #pragma unroll
      for (int j=0;j<4;j++){
        int kin = j*16 + l16;
        #pragma unroll
        for (int r=0;r<4;r++){
          bool keep = !diag || (kin <= qbase + r);
          float p = keep ? __builtin_amdgcn_exp2f(sacc[j][r]*CS) : 0.f;
          lp[r] += p;
          Ps[wave][quad*4+r][j*16+l16] = f2bf(p * bf2f(g4[r][j]));
        }
      }

      // ---- P·V ----
      #pragma unroll
      for (int ks2=0; ks2<2; ks2++){
        short8v pf = *(short8v*)&Ps[wave][l16][ks2*32 + quad*8];
        #pragma unroll
        for (int dt=0; dt<8; dt++){
          short8v vf = *(short8v*)&Vts[dt*16 + l16][((ks2*4+quad)^l7)*8];
          oacc[dt] = __builtin_amdgcn_mfma_f32_16x16x32_bf16(pf, vf, oacc[dt], 0,0,0);
        }
      }
    }

    #pragma unroll
    for (int r=0;r<4;r++)
      #pragma unroll
      for (int off=1; off<16; off<<=1)
        lp[r] += __shfl_xor(lp[r], off, 64);
    #pragma unroll
    for (int r=0;r<4;r++){
      float inv = __builtin_amdgcn_rcpf(lp[r]);
      size_t orow = (size_t)(b*2048 + qt*64 + wave*16 + quad*4 + r);
      #pragma unroll
      for (int dt=0;dt<8;dt++)
        O[orow*2048 + h*128 + dt*16 + l16] = f2bf(oacc[dt][r]*inv);
    }
  }
}

// ---------------- launch ----------------
extern "C" void kernel_launch(void* const* d_in, const int* in_sizes, int n_in,
                              void* d_out, int out_size, void* d_ws, size_t ws_size,
                              hipStream_t stream){
  const float* x    = (const float*)d_in[0];
  const float* fcos = (const float*)d_in[2];
  const float* fsin = (const float*)d_in[3];
  const float* wq   = (const float*)d_in[4];
  const float* wk   = (const float*)d_in[5];
  const float* wv   = (const float*)d_in[6];
  const float* wo   = (const float*)d_in[7];
  const float* waq  = (const float*)d_in[8];
  const float* wak  = (const float*)d_in[9];
  float* out = (float*)d_out;

  char* ws = (char*)d_ws;
  size_t off = 0;
  short* xb   = (short*)(ws + off); off += (size_t)4096*2048*2;   // x bf16; later G (gate)
  short* Wcat = (short*)(ws + off); off += (size_t)NW_*2048*2;    // fused weights; later O
  short* wob  = (short*)(ws + off); off += (size_t)2048*2048*2;
  short* XQKV = (short*)(ws + off); off += (size_t)4096*NW_*2;    // [Q|qh|kh|K|pad|(V unused)]
  short* Vtb  = (short*)(ws + off); off += (size_t)2048*4096*2;   // V transposed
  short* G    = xb;    // gate overlays xb (x dead after gemm_qkv)
  short* Ob   = Wcat;  // flash output overlays Wcat (dead after gemm_qkv)

  cvt_k<<<8192,256,0,stream>>>(x, xb, 8388608);
  cvt_w<<<dim3(4096,7),256,0,stream>>>(wq, waq, wak, wk, wv, wo, Wcat, wob);

  gemm_qkv<<<dim3(400),512,0,stream>>>(xb, Wcat, XQKV, Vtb);

  rope_k<<<16384,256,0,stream>>>(XQKV, fcos, fsin);
  gate_k<<<dim3(32,32,2),256,0,stream>>>(XQKV, G);

  flash_k<<<dim3(16,16,2),256,0,stream>>>(XQKV, Vtb, G, fcos, fsin, Ob);

  gemm_nt_f32<<<dim3(32,16),256,0,stream>>>(Ob, wob, out, 4096, 2048, 2048);
}